// Round 5
// baseline (478.881 us; speedup 1.0000x reference)
//
#include <hip/hip_runtime.h>
#include <math.h>

#define B_   8
#define N_   1024
#define T_   16
#define E_   512
#define H_   8
#define DH_  64
#define KNN_ 16

typedef __attribute__((ext_vector_type(8))) _Float16 half8;
typedef __attribute__((ext_vector_type(2))) _Float16 half2v;
typedef __attribute__((ext_vector_type(4))) float    f32x4;

// ---------------------------------------------------------------------------
// Kernel 1: KNN over positions + log_w. Unchanged (verified passing R3/R4).
// ---------------------------------------------------------------------------
__global__ __launch_bounds__(256) void knn_kernel(const float* __restrict__ pos,
                                                  const float* __restrict__ tau_p,
                                                  int* __restrict__ knn_idx,
                                                  float* __restrict__ logw) {
    __shared__ float dist[N_];
    __shared__ float rval[4];
    __shared__ int   ridx[4];
    __shared__ float sel_d[KNN_];
    __shared__ int   sel_i[KNN_];

    const int i = blockIdx.x;
    const int t = threadIdx.x;

    const float px = pos[2 * i], py = pos[2 * i + 1];
    const float xi2 = px * px + py * py;

    for (int j = t; j < N_; j += 256) {
        const float qx = pos[2 * j], qy = pos[2 * j + 1];
        const float xj2 = qx * qx + qy * qy;
        float d2 = xi2 + xj2 - 2.0f * (px * qx + py * qy);
        d2 = fmaxf(d2, 0.0f);
        const float d = sqrtf(d2 + 1e-9f);
        dist[j] = (j == i) ? __builtin_inff() : d;
    }
    __syncthreads();

    for (int k = 0; k < KNN_; ++k) {
        float best = __builtin_inff();
        int bi = 0x7fffffff;
        for (int j = t; j < N_; j += 256) {
            const float d = dist[j];
            if (d < best) { best = d; bi = j; }
        }
        for (int off = 32; off >= 1; off >>= 1) {
            const float ov = __shfl_down(best, off);
            const int   oi = __shfl_down(bi, off);
            if (ov < best || (ov == best && oi < bi)) { best = ov; bi = oi; }
        }
        const int wave = t >> 6;
        if ((t & 63) == 0) { rval[wave] = best; ridx[wave] = bi; }
        __syncthreads();
        if (t == 0) {
            for (int w = 1; w < 4; ++w) {
                if (rval[w] < best || (rval[w] == best && ridx[w] < bi)) { best = rval[w]; bi = ridx[w]; }
            }
            sel_d[k] = best;
            sel_i[k] = bi;
            dist[bi] = __builtin_inff();
        }
        __syncthreads();
    }

    if (t < KNN_) {
        float mean = 0.0f;
        for (int k = 0; k < KNN_; ++k) mean += sel_d[k];
        mean *= (1.0f / KNN_);
        const float scale = fmaxf(mean, 1.1920929e-7f);
        const float tau_safe = fmaxf(tau_p[0], 1e-4f);
        float lw = -(sel_d[t] / scale) / tau_safe;
        lw = fminf(fmaxf(lw, -10.0f), 0.0f);
        logw[i * KNN_ + t]    = lw;
        knn_idx[i * KNN_ + t] = sel_i[t];
    }
}

// ---------------------------------------------------------------------------
// Kernel 2: h_last / neigh_mean. Unchanged (verified passing R3/R4).
// ---------------------------------------------------------------------------
__global__ __launch_bounds__(256) void last_mean_kernel(const float* __restrict__ hidden,
                                                        float* __restrict__ h_last,
                                                        float* __restrict__ neigh_mean) {
    const int idx = blockIdx.x * 256 + threadIdx.x;
    const int e4 = idx & (E_ / 4 - 1);
    const int bn = idx >> 7;
    const float4* h = (const float4*)hidden;
    const size_t base = (size_t)bn * (T_ * (E_ / 4)) + e4;
    const float4 a = h[base + 12 * (E_ / 4)];
    const float4 b = h[base + 13 * (E_ / 4)];
    const float4 c = h[base + 14 * (E_ / 4)];
    const float4 d = h[base + 15 * (E_ / 4)];
    ((float4*)h_last)[idx] = d;
    float4 m;
    m.x = (a.x + b.x + c.x + d.x) * 0.25f;
    m.y = (a.y + b.y + c.y + d.y) * 0.25f;
    m.z = (a.z + b.z + c.z + d.z) * 0.25f;
    m.w = (a.w + b.w + c.w + d.w) * 0.25f;
    ((float4*)neigh_mean)[idx] = m;
}

// ---------------------------------------------------------------------------
// Split-fp16 MFMA GEMM (verified R4). Output type templated: fp32 for Q and
// final out; fp16 for K/V (halves attn gather traffic; adds rel err 2^-11,
// far under the 0.0039 absmax floor).
// ---------------------------------------------------------------------------
__device__ __forceinline__ void split_store(unsigned short* __restrict__ Hs,
                                            unsigned short* __restrict__ Ls,
                                            int byt, float4 v) {
    union { _Float16 h[4]; uint2 u; } Hu, Lu;
    const float* f = (const float*)&v;
#pragma unroll
    for (int j = 0; j < 4; ++j) {
        const _Float16 hh = (_Float16)f[j];
        Hu.h[j] = hh;
        Lu.h[j] = (_Float16)(f[j] - (float)hh);   // exact residual
    }
    *(uint2*)((char*)Hs + byt) = Hu.u;
    *(uint2*)((char*)Ls + byt) = Lu.u;
}

template <typename OT>
__device__ __forceinline__ void gemm_split_f16(const float* __restrict__ A,
                                               const float* __restrict__ Wt,
                                               const float* __restrict__ bias,
                                               OT* __restrict__ C) {
    __shared__ unsigned short AhS[128 * 64];
    __shared__ unsigned short AlS[128 * 64];
    __shared__ unsigned short WhS[128 * 64];
    __shared__ unsigned short WlS[128 * 64];

    const int t    = threadIdx.x;
    const int m0   = blockIdx.x * 128;
    const int j0   = blockIdx.y * 128;
    const int lane = t & 63;
    const int wv   = t >> 6;
    const int wm   = wv >> 1;
    const int wn   = wv & 1;
    const int lr   = lane & 15;
    const int kg   = lane >> 4;

    float4 ra[8], rw[8];
#pragma unroll
    for (int s = 0; s < 8; ++s) {
        const int f4 = s * 256 + t;
        const int row = f4 >> 4, k4 = f4 & 15;
        ra[s] = *(const float4*)(A  + (size_t)(m0 + row) * 512 + k4 * 4);
        rw[s] = *(const float4*)(Wt + (size_t)(j0 + row) * 512 + k4 * 4);
    }

    f32x4 acc[4][4];
    const f32x4 zero = {0.0f, 0.0f, 0.0f, 0.0f};
#pragma unroll
    for (int f = 0; f < 4; ++f)
#pragma unroll
        for (int g = 0; g < 4; ++g) acc[f][g] = zero;

    for (int it = 0; it < 8; ++it) {
        __syncthreads();
#pragma unroll
        for (int s = 0; s < 8; ++s) {
            const int f4 = s * 256 + t;
            const int row = f4 >> 4, k4 = f4 & 15;
            const int byt = (row << 7) + ((k4 * 8) ^ ((row & 7) << 4));
            split_store(AhS, AlS, byt, ra[s]);
            split_store(WhS, WlS, byt, rw[s]);
        }
        __syncthreads();
        if (it < 7) {
            const int kc = (it + 1) * 64;
#pragma unroll
            for (int s = 0; s < 8; ++s) {
                const int f4 = s * 256 + t;
                const int row = f4 >> 4, k4 = f4 & 15;
                ra[s] = *(const float4*)(A  + (size_t)(m0 + row) * 512 + kc + k4 * 4);
                rw[s] = *(const float4*)(Wt + (size_t)(j0 + row) * 512 + kc + k4 * 4);
            }
        }
#pragma unroll
        for (int ks = 0; ks < 2; ++ks) {
            half8 ah[4], al[4], wh[4], wl[4];
#pragma unroll
            for (int f = 0; f < 4; ++f) {
                const int row = wm * 64 + f * 16 + lr;
                const int byt = (row << 7) + (((ks * 64) + (kg * 16)) ^ ((row & 7) << 4));
                ah[f] = *(const half8*)((const char*)AhS + byt);
                al[f] = *(const half8*)((const char*)AlS + byt);
            }
#pragma unroll
            for (int g = 0; g < 4; ++g) {
                const int row = wn * 64 + g * 16 + lr;
                const int byt = (row << 7) + (((ks * 64) + (kg * 16)) ^ ((row & 7) << 4));
                wh[g] = *(const half8*)((const char*)WhS + byt);
                wl[g] = *(const half8*)((const char*)WlS + byt);
            }
#pragma unroll
            for (int f = 0; f < 4; ++f)
#pragma unroll
                for (int g = 0; g < 4; ++g)
                    acc[f][g] = __builtin_amdgcn_mfma_f32_16x16x32_f16(ah[f], wh[g], acc[f][g], 0, 0, 0);
#pragma unroll
            for (int f = 0; f < 4; ++f)
#pragma unroll
                for (int g = 0; g < 4; ++g)
                    acc[f][g] = __builtin_amdgcn_mfma_f32_16x16x32_f16(ah[f], wl[g], acc[f][g], 0, 0, 0);
#pragma unroll
            for (int f = 0; f < 4; ++f)
#pragma unroll
                for (int g = 0; g < 4; ++g)
                    acc[f][g] = __builtin_amdgcn_mfma_f32_16x16x32_f16(al[f], wh[g], acc[f][g], 0, 0, 0);
        }
    }

#pragma unroll
    for (int g = 0; g < 4; ++g) {
        const int n  = j0 + wn * 64 + g * 16 + lr;
        const float bn = bias[n];
#pragma unroll
        for (int f = 0; f < 4; ++f) {
            const int mrow = m0 + wm * 64 + f * 16 + kg * 4;
#pragma unroll
            for (int q = 0; q < 4; ++q)
                C[(size_t)(mrow + q) * 512 + n] = (OT)(acc[f][g][q] + bn);
        }
    }
}

__global__ __launch_bounds__(256, 2) void qkv_gemm_kernel(const float* __restrict__ h_last,
                                                          const float* __restrict__ nmean,
                                                          const float* __restrict__ Wq,
                                                          const float* __restrict__ Wk,
                                                          const float* __restrict__ Wv,
                                                          const float* __restrict__ bq,
                                                          const float* __restrict__ bk,
                                                          const float* __restrict__ bv,
                                                          float* __restrict__ Qo,
                                                          _Float16* __restrict__ Ko,
                                                          _Float16* __restrict__ Vo) {
    const int which = blockIdx.z;
    if (which == 0) {
        gemm_split_f16<float>(h_last, Wq, bq, Qo);
    } else if (which == 1) {
        gemm_split_f16<_Float16>(nmean, Wk, bk, Ko);
    } else {
        gemm_split_f16<_Float16>(nmean, Wv, bv, Vo);
    }
}

__global__ __launch_bounds__(256, 2) void out_gemm_kernel(const float* __restrict__ ctx,
                                                          const float* __restrict__ Wo,
                                                          const float* __restrict__ bo,
                                                          float* __restrict__ out) {
    gemm_split_f16<float>(ctx, Wo, bo, out);
}

// ---------------------------------------------------------------------------
// Kernel 4: attention, fp16 K/V + XCD-aware block remap.
// bn = (bid&7)*1024 + (bid>>3): with round-robin bid->XCD dispatch, XCD x
// processes exactly batch b=x => per-XCD K/V working set drops 8x
// (16MB fp16 vs previous 256MB fp32 spread) -> L2 hit rate up.
// ---------------------------------------------------------------------------
__global__ __launch_bounds__(256) void attn_kernel(const float* __restrict__ Q,
                                                   const _Float16* __restrict__ Kf,
                                                   const _Float16* __restrict__ Vf,
                                                   const int* __restrict__ knn_idx,
                                                   const float* __restrict__ logw,
                                                   float* __restrict__ ctx) {
    const int bid = blockIdx.x;
    const int bn  = ((bid & 7) << 10) | (bid >> 3);   // b = bid&7, n = bid>>3
    const int n   = bn & (N_ - 1);
    const int b   = bn >> 10;
    const int t   = threadIdx.x;

    __shared__ int   idxs[KNN_];
    __shared__ float lws[KNN_];
    if (t < KNN_) {
        idxs[t] = knn_idx[n * KNN_ + t];
        lws[t]  = logw[n * KNN_ + t];
    }
    __syncthreads();

    const float2 q = ((const float2*)Q)[(size_t)bn * 256 + t];

    float logits[KNN_];
#pragma unroll
    for (int k = 0; k < KNN_; ++k) {
        const int j = idxs[k];
        const half2v kv = ((const half2v*)Kf)[((size_t)(b * N_ + j)) * 256 + t];
        float d = q.x * (float)kv.x + q.y * (float)kv.y;
        d += __shfl_xor(d, 1);
        d += __shfl_xor(d, 2);
        d += __shfl_xor(d, 4);
        d += __shfl_xor(d, 8);
        d += __shfl_xor(d, 16);
        logits[k] = d * 0.125f + lws[k];
    }

    float m = -__builtin_inff();
#pragma unroll
    for (int k = 0; k < KNN_; ++k) m = fmaxf(m, logits[k]);
    float p[KNN_];
    float s = 0.0f;
#pragma unroll
    for (int k = 0; k < KNN_; ++k) { p[k] = expf(logits[k] - m); s += p[k]; }
    const float inv = 1.0f / s;

    float2 acc = make_float2(0.0f, 0.0f);
#pragma unroll
    for (int k = 0; k < KNN_; ++k) {
        const int j = idxs[k];
        const half2v vv = ((const half2v*)Vf)[((size_t)(b * N_ + j)) * 256 + t];
        const float w = p[k] * inv;
        acc.x = fmaf(w, (float)vv.x, acc.x);
        acc.y = fmaf(w, (float)vv.y, acc.y);
    }
    ((float2*)ctx)[(size_t)bn * 256 + t] = acc;
}

// ---------------------------------------------------------------------------
extern "C" void kernel_launch(void* const* d_in, const int* in_sizes, int n_in,
                              void* d_out, int out_size, void* d_ws, size_t ws_size,
                              hipStream_t stream) {
    const float* hidden = (const float*)d_in[0];
    const float* pos    = (const float*)d_in[1];
    const float* Wq     = (const float*)d_in[2];
    const float* bq     = (const float*)d_in[3];
    const float* Wk     = (const float*)d_in[4];
    const float* bk     = (const float*)d_in[5];
    const float* Wv     = (const float*)d_in[6];
    const float* bv     = (const float*)d_in[7];
    const float* Wo     = (const float*)d_in[8];
    const float* bo     = (const float*)d_in[9];
    const float* tau    = (const float*)d_in[10];

    float* ws      = (float*)d_ws;
    const size_t SZ = (size_t)B_ * N_ * E_;       // 4,194,304
    float*    h_last  = ws;                       // later reused as ctx
    float*    nmean   = ws + SZ;
    _Float16* Kh      = (_Float16*)(ws + 2 * SZ);            // SZ halves
    _Float16* Vh      = (_Float16*)(ws + 2 * SZ + SZ / 2);   // SZ halves
    int*      knn_idx = (int*)(ws + 3 * SZ);
    float*    logw    = ws + 3 * SZ + N_ * KNN_;
    float*    Qb      = (float*)d_out;            // d_out doubles as Q scratch
    float*    out     = (float*)d_out;

    knn_kernel<<<N_, 256, 0, stream>>>(pos, tau, knn_idx, logw);
    last_mean_kernel<<<(B_ * N_ * E_ / 4) / 256, 256, 0, stream>>>(hidden, h_last, nmean);

    dim3 gqkv(B_ * N_ / 128, E_ / 128, 3);
    qkv_gemm_kernel<<<gqkv, 256, 0, stream>>>(h_last, nmean, Wq, Wk, Wv, bq, bk, bv, Qb, Kh, Vh);

    attn_kernel<<<B_ * N_, 256, 0, stream>>>(Qb, Kh, Vh, knn_idx, logw, h_last /* ctx */);

    dim3 gout(B_ * N_ / 128, E_ / 128, 1);
    out_gemm_kernel<<<gout, 256, 0, stream>>>(h_last, Wo, bo, out);
}

// Round 6
// 441.765 us; speedup vs baseline: 1.0840x; 1.0840x over previous
//
#include <hip/hip_runtime.h>
#include <math.h>

#define B_   8
#define N_   1024
#define T_   16
#define E_   512
#define H_   8
#define DH_  64
#define KNN_ 16

typedef __attribute__((ext_vector_type(8))) _Float16 half8;
typedef __attribute__((ext_vector_type(4))) _Float16 half4;
typedef __attribute__((ext_vector_type(2))) _Float16 half2v;
typedef __attribute__((ext_vector_type(4))) float    f32x4;

// ---------------------------------------------------------------------------
// Kernel 1: KNN over positions + log_w. Unchanged (verified R3/R4/R5).
// ---------------------------------------------------------------------------
__global__ __launch_bounds__(256) void knn_kernel(const float* __restrict__ pos,
                                                  const float* __restrict__ tau_p,
                                                  int* __restrict__ knn_idx,
                                                  float* __restrict__ logw) {
    __shared__ float dist[N_];
    __shared__ float rval[4];
    __shared__ int   ridx[4];
    __shared__ float sel_d[KNN_];
    __shared__ int   sel_i[KNN_];

    const int i = blockIdx.x;
    const int t = threadIdx.x;

    const float px = pos[2 * i], py = pos[2 * i + 1];
    const float xi2 = px * px + py * py;

    for (int j = t; j < N_; j += 256) {
        const float qx = pos[2 * j], qy = pos[2 * j + 1];
        const float xj2 = qx * qx + qy * qy;
        float d2 = xi2 + xj2 - 2.0f * (px * qx + py * qy);
        d2 = fmaxf(d2, 0.0f);
        const float d = sqrtf(d2 + 1e-9f);
        dist[j] = (j == i) ? __builtin_inff() : d;
    }
    __syncthreads();

    for (int k = 0; k < KNN_; ++k) {
        float best = __builtin_inff();
        int bi = 0x7fffffff;
        for (int j = t; j < N_; j += 256) {
            const float d = dist[j];
            if (d < best) { best = d; bi = j; }
        }
        for (int off = 32; off >= 1; off >>= 1) {
            const float ov = __shfl_down(best, off);
            const int   oi = __shfl_down(bi, off);
            if (ov < best || (ov == best && oi < bi)) { best = ov; bi = oi; }
        }
        const int wave = t >> 6;
        if ((t & 63) == 0) { rval[wave] = best; ridx[wave] = bi; }
        __syncthreads();
        if (t == 0) {
            for (int w = 1; w < 4; ++w) {
                if (rval[w] < best || (rval[w] == best && ridx[w] < bi)) { best = rval[w]; bi = ridx[w]; }
            }
            sel_d[k] = best;
            sel_i[k] = bi;
            dist[bi] = __builtin_inff();
        }
        __syncthreads();
    }

    if (t < KNN_) {
        float mean = 0.0f;
        for (int k = 0; k < KNN_; ++k) mean += sel_d[k];
        mean *= (1.0f / KNN_);
        const float scale = fmaxf(mean, 1.1920929e-7f);
        const float tau_safe = fmaxf(tau_p[0], 1e-4f);
        float lw = -(sel_d[t] / scale) / tau_safe;
        lw = fminf(fmaxf(lw, -10.0f), 0.0f);
        logw[i * KNN_ + t]    = lw;
        knn_idx[i * KNN_ + t] = sel_i[t];
    }
}

// ---------------------------------------------------------------------------
// Kernel 2: weight split. Wq/Wk/Wv/Wo fp32 -> (hi,lo) f16 pairs, laid out as
// Wsp[mat*2*WS .. ]: hi at +0, lo at +WS (WS = 512*512).
// ---------------------------------------------------------------------------
__global__ __launch_bounds__(256) void wsplit_kernel(const float* __restrict__ Wq,
                                                     const float* __restrict__ Wk,
                                                     const float* __restrict__ Wv,
                                                     const float* __restrict__ Wo,
                                                     _Float16* __restrict__ dst) {
    const int id  = blockIdx.x * 256 + threadIdx.x;   // 0..262143 (float4 units)
    const int mat = id >> 16;                         // 65536 float4 per matrix
    const int i   = id & 65535;
    const float* src = (mat == 0) ? Wq : (mat == 1) ? Wk : (mat == 2) ? Wv : Wo;
    const float4 v = ((const float4*)src)[i];
    half4 hi, lo;
    const float* f = (const float*)&v;
#pragma unroll
    for (int j = 0; j < 4; ++j) {
        const _Float16 hh = (_Float16)f[j];
        hi[j] = hh;
        lo[j] = (_Float16)(f[j] - (float)hh);
    }
    _Float16* dh = dst + (size_t)mat * 2 * 262144;
    *(half4*)(dh + (size_t)i * 4)          = hi;
    *(half4*)(dh + 262144 + (size_t)i * 4) = lo;
}

// ---------------------------------------------------------------------------
// Kernel 3: h_last/neigh_mean straight to f16 (GEMM A-operands).
// Same read bytes as before; write bytes halved.
// ---------------------------------------------------------------------------
__global__ __launch_bounds__(256) void last_mean_kernel(const float* __restrict__ hidden,
                                                        _Float16* __restrict__ hlast_h,
                                                        _Float16* __restrict__ nmean_h) {
    const int idx = blockIdx.x * 256 + threadIdx.x;   // float4 index, B*N*E/4 total
    const int e4 = idx & (E_ / 4 - 1);
    const int bn = idx >> 7;
    const float4* h = (const float4*)hidden;
    const size_t base = (size_t)bn * (T_ * (E_ / 4)) + e4;
    const float4 a = h[base + 12 * (E_ / 4)];
    const float4 b = h[base + 13 * (E_ / 4)];
    const float4 c = h[base + 14 * (E_ / 4)];
    const float4 d = h[base + 15 * (E_ / 4)];
    half4 hl, nm;
    const float* df = (const float*)&d;
    const float* af = (const float*)&a;
    const float* bf = (const float*)&b;
    const float* cf = (const float*)&c;
#pragma unroll
    for (int j = 0; j < 4; ++j) {
        hl[j] = (_Float16)df[j];
        nm[j] = (_Float16)((af[j] + bf[j] + cf[j] + df[j]) * 0.25f);
    }
    *(half4*)(hlast_h + (size_t)idx * 4) = hl;
    *(half4*)(nmean_h + (size_t)idx * 4) = nm;
}

// ---------------------------------------------------------------------------
// f16 MFMA GEMM, m97 structure: global_load_lds(16B) staging, linear LDS
// (both sides linear, rule #21), 2-barrier K-loop, 128x128 tile, BK=64,
// 4 waves (2x2, 64x64 each), 16x16x32 f16 MFMA (frag indexing verified R4).
// PASSES=2: C = Ah*(Wh+Wl)      (Q/K/V; output rounded to f16 anyway)
// PASSES=3: C = Ah*Wh + Ah*Wl + Al*Wh   (final out, fp32-grade)
// LDS: PASSES==2 -> 3 arrays x 16KB = 48KB (3 blocks/CU); ==3 -> 64KB (2).
// ---------------------------------------------------------------------------
__device__ __forceinline__ void gload16(const void* g, void* l) {
    __builtin_amdgcn_global_load_lds((const __attribute__((address_space(1))) void*)g,
                                     (__attribute__((address_space(3))) void*)l, 16, 0, 0);
}

template <int PASSES, typename OT>
__device__ __forceinline__ void gemm_f16(const _Float16* __restrict__ Ah,
                                         const _Float16* __restrict__ Al,
                                         const _Float16* __restrict__ Wh,
                                         const _Float16* __restrict__ Wl,
                                         const float* __restrict__ bias,
                                         OT* __restrict__ C) {
    constexpr int NARR  = (PASSES == 3) ? 4 : 3;
    constexpr int WHOFF = (PASSES == 3) ? 32768 : 16384;   // LDS byte offset of Wh
    __shared__ unsigned short lds[NARR * 8192];            // NARR x 16KB

    const int t    = threadIdx.x;
    const int m0   = blockIdx.x * 128;
    const int j0   = blockIdx.y * 128;
    const int lane = t & 63;
    const int wv   = t >> 6;
    const int wm   = wv >> 1, wn = wv & 1;
    const int lr   = lane & 15, kg = lane >> 4;
    // per-lane global sub-offset within an 8-row slab (matches HW lane*16 LDS stride)
    const int lsub = (lane >> 3) * 1024 + (lane & 7) * 16;

    f32x4 acc[4][4];
    const f32x4 zero = {0.0f, 0.0f, 0.0f, 0.0f};
#pragma unroll
    for (int f = 0; f < 4; ++f)
#pragma unroll
        for (int g = 0; g < 4; ++g) acc[f][g] = zero;

    for (int it = 0; it < 8; ++it) {
        const size_t kb = (size_t)(it * 64) * 2;           // byte offset in 1024B rows
        const char* gA  = (const char*)Ah + (size_t)m0 * 1024 + kb;
        const char* gWh = (const char*)Wh + (size_t)j0 * 1024 + kb;
        const char* gWl = (const char*)Wl + (size_t)j0 * 1024 + kb;
        const char* gAl = (PASSES == 3) ? (const char*)Al + (size_t)m0 * 1024 + kb : (const char*)0;
#pragma unroll
        for (int jj = 0; jj < NARR * 4; ++jj) {            // flat slab split over 4 waves
            const int j = wv * (NARR * 4) + jj;
            const int arr = j >> 4, slab = j & 15;         // slab = 8 rows = 1KB
            const char* gb;
            if (PASSES == 3)
                gb = (arr == 0) ? gA : (arr == 1) ? gAl : (arr == 2) ? gWh : gWl;
            else
                gb = (arr == 0) ? gA : (arr == 1) ? gWh : gWl;
            gload16(gb + (size_t)slab * 8192 + lsub, (char*)lds + j * 1024);
        }
        __syncthreads();   // compiler drains vmcnt(0) before s_barrier -> staged data ready

#pragma unroll
        for (int ks = 0; ks < 2; ++ks) {
            const int ko = ks * 64 + kg * 16;
            half8 ah[4], al[4], wh[4], wl[4];
#pragma unroll
            for (int f = 0; f < 4; ++f) {
                const int abyt = (wm * 64 + f * 16 + lr) * 128 + ko;
                ah[f] = *(const half8*)((const char*)lds + abyt);
                if (PASSES == 3) al[f] = *(const half8*)((const char*)lds + 16384 + abyt);
            }
#pragma unroll
            for (int g = 0; g < 4; ++g) {
                const int wbyt = (wn * 64 + g * 16 + lr) * 128 + ko;
                wh[g] = *(const half8*)((const char*)lds + WHOFF + wbyt);
                wl[g] = *(const half8*)((const char*)lds + WHOFF + 16384 + wbyt);
            }
#pragma unroll
            for (int f = 0; f < 4; ++f)
#pragma unroll
                for (int g = 0; g < 4; ++g)
                    acc[f][g] = __builtin_amdgcn_mfma_f32_16x16x32_f16(ah[f], wh[g], acc[f][g], 0, 0, 0);
#pragma unroll
            for (int f = 0; f < 4; ++f)
#pragma unroll
                for (int g = 0; g < 4; ++g)
                    acc[f][g] = __builtin_amdgcn_mfma_f32_16x16x32_f16(ah[f], wl[g], acc[f][g], 0, 0, 0);
            if (PASSES == 3) {
#pragma unroll
                for (int f = 0; f < 4; ++f)
#pragma unroll
                    for (int g = 0; g < 4; ++g)
                        acc[f][g] = __builtin_amdgcn_mfma_f32_16x16x32_f16(al[f], wh[g], acc[f][g], 0, 0, 0);
            }
        }
        if (it < 7) __syncthreads();                       // protect LDS before next stage
    }

    // Epilogue (D layout col=lane&15, row=(lane>>4)*4+q — verified R4)
#pragma unroll
    for (int g = 0; g < 4; ++g) {
        const int n = j0 + wn * 64 + g * 16 + lr;
        const float bn_ = bias[n];
#pragma unroll
        for (int f = 0; f < 4; ++f) {
            const int mrow = m0 + wm * 64 + f * 16 + kg * 4;
#pragma unroll
            for (int q = 0; q < 4; ++q)
                C[(size_t)(mrow + q) * 512 + n] = (OT)(acc[f][g][q] + bn_);
        }
    }
}

__global__ __launch_bounds__(256, 3) void qkv_gemm_kernel(const _Float16* __restrict__ hlast_h,
                                                          const _Float16* __restrict__ nmean_h,
                                                          const _Float16* __restrict__ Wsp,
                                                          const float* __restrict__ bq,
                                                          const float* __restrict__ bk,
                                                          const float* __restrict__ bv,
                                                          _Float16* __restrict__ Qh,
                                                          _Float16* __restrict__ Kh,
                                                          _Float16* __restrict__ Vh) {
    const int which = blockIdx.z;
    const size_t WS = 262144;
    const _Float16* A  = (which == 0) ? hlast_h : nmean_h;
    const _Float16* wh = Wsp + (size_t)which * 2 * WS;
    const _Float16* wl = wh + WS;
    const float* bias  = (which == 0) ? bq : (which == 1) ? bk : bv;
    _Float16* Cc       = (which == 0) ? Qh : (which == 1) ? Kh : Vh;
    gemm_f16<2, _Float16>(A, (const _Float16*)0, wh, wl, bias, Cc);
}

__global__ __launch_bounds__(256, 2) void out_gemm_kernel(const _Float16* __restrict__ ctx_h,
                                                          const _Float16* __restrict__ ctx_l,
                                                          const _Float16* __restrict__ Wsp,
                                                          const float* __restrict__ bo,
                                                          float* __restrict__ out) {
    const size_t WS = 262144;
    gemm_f16<3, float>(ctx_h, ctx_l, Wsp + 6 * WS, Wsp + 7 * WS, bo, out);
}

// ---------------------------------------------------------------------------
// Kernel 5: attention. f16 Q/K/V; ctx written as (hi,lo) f16 pair for the
// 3-pass out-GEMM. XCD-aware remap kept (mechanically sound, cost-free).
// ---------------------------------------------------------------------------
__global__ __launch_bounds__(256) void attn_kernel(const _Float16* __restrict__ Qh,
                                                   const _Float16* __restrict__ Kf,
                                                   const _Float16* __restrict__ Vf,
                                                   const int* __restrict__ knn_idx,
                                                   const float* __restrict__ logw,
                                                   _Float16* __restrict__ ctx_h,
                                                   _Float16* __restrict__ ctx_l) {
    const int bid = blockIdx.x;
    const int bn  = ((bid & 7) << 10) | (bid >> 3);
    const int n   = bn & (N_ - 1);
    const int b   = bn >> 10;
    const int t   = threadIdx.x;

    __shared__ int   idxs[KNN_];
    __shared__ float lws[KNN_];
    if (t < KNN_) {
        idxs[t] = knn_idx[n * KNN_ + t];
        lws[t]  = logw[n * KNN_ + t];
    }
    __syncthreads();

    const half2v q2 = ((const half2v*)Qh)[(size_t)bn * 256 + t];
    const float qx = (float)q2.x, qy = (float)q2.y;

    float logits[KNN_];
#pragma unroll
    for (int k = 0; k < KNN_; ++k) {
        const int j = idxs[k];
        const half2v kv = ((const half2v*)Kf)[((size_t)(b * N_ + j)) * 256 + t];
        float d = qx * (float)kv.x + qy * (float)kv.y;
        d += __shfl_xor(d, 1);
        d += __shfl_xor(d, 2);
        d += __shfl_xor(d, 4);
        d += __shfl_xor(d, 8);
        d += __shfl_xor(d, 16);
        logits[k] = d * 0.125f + lws[k];
    }

    float m = -__builtin_inff();
#pragma unroll
    for (int k = 0; k < KNN_; ++k) m = fmaxf(m, logits[k]);
    float p[KNN_];
    float s = 0.0f;
#pragma unroll
    for (int k = 0; k < KNN_; ++k) { p[k] = expf(logits[k] - m); s += p[k]; }
    const float inv = 1.0f / s;

    float2 acc = make_float2(0.0f, 0.0f);
#pragma unroll
    for (int k = 0; k < KNN_; ++k) {
        const int j = idxs[k];
        const half2v vv = ((const half2v*)Vf)[((size_t)(b * N_ + j)) * 256 + t];
        const float w = p[k] * inv;
        acc.x = fmaf(w, (float)vv.x, acc.x);
        acc.y = fmaf(w, (float)vv.y, acc.y);
    }
    half2v hx, lx;
    hx.x = (_Float16)acc.x;  lx.x = (_Float16)(acc.x - (float)hx.x);
    hx.y = (_Float16)acc.y;  lx.y = (_Float16)(acc.y - (float)hx.y);
    ((half2v*)ctx_h)[(size_t)bn * 256 + t] = hx;
    ((half2v*)ctx_l)[(size_t)bn * 256 + t] = lx;
}

// ---------------------------------------------------------------------------
extern "C" void kernel_launch(void* const* d_in, const int* in_sizes, int n_in,
                              void* d_out, int out_size, void* d_ws, size_t ws_size,
                              hipStream_t stream) {
    const float* hidden = (const float*)d_in[0];
    const float* pos    = (const float*)d_in[1];
    const float* Wq     = (const float*)d_in[2];
    const float* bq     = (const float*)d_in[3];
    const float* Wk     = (const float*)d_in[4];
    const float* bk     = (const float*)d_in[5];
    const float* Wv     = (const float*)d_in[6];
    const float* bv     = (const float*)d_in[7];
    const float* Wo     = (const float*)d_in[8];
    const float* bo     = (const float*)d_in[9];
    const float* tau    = (const float*)d_in[10];

    _Float16* hp = (_Float16*)d_ws;
    const size_t SZH = (size_t)B_ * N_ * E_;   // 4,194,304 halves per array
    const size_t WS  = 262144;                 // 512*512 halves
    _Float16* hlast_h = hp;
    _Float16* nmean_h = hp + SZH;
    _Float16* Qh      = hp + 2 * SZH;
    _Float16* Kh      = hp + 3 * SZH;
    _Float16* Vh      = hp + 4 * SZH;
    _Float16* ctx_h   = hp + 5 * SZH;
    _Float16* ctx_l   = hp + 6 * SZH;
    _Float16* Wsp     = hp + 7 * SZH;          // 8 * WS halves
    int*      knn_idx = (int*)(hp + 7 * SZH + 8 * WS);
    float*    logw    = (float*)(knn_idx + N_ * KNN_);
    float*    out     = (float*)d_out;

    knn_kernel<<<N_, 256, 0, stream>>>(pos, tau, knn_idx, logw);
    wsplit_kernel<<<1024, 256, 0, stream>>>(Wq, Wk, Wv, Wo, Wsp);
    last_mean_kernel<<<(B_ * N_ * E_ / 4) / 256, 256, 0, stream>>>(hidden, hlast_h, nmean_h);

    dim3 gqkv(B_ * N_ / 128, E_ / 128, 3);
    qkv_gemm_kernel<<<gqkv, 256, 0, stream>>>(hlast_h, nmean_h, Wsp, bq, bk, bv, Qh, Kh, Vh);

    attn_kernel<<<B_ * N_, 256, 0, stream>>>(Qh, Kh, Vh, knn_idx, logw, ctx_h, ctx_l);

    dim3 gout(B_ * N_ / 128, E_ / 128, 1);
    out_gemm_kernel<<<gout, 256, 0, stream>>>(ctx_h, ctx_l, Wsp, bo, out);
}

// Round 7
// 431.273 us; speedup vs baseline: 1.1104x; 1.0243x over previous
//
#include <hip/hip_runtime.h>
#include <math.h>

#define B_   8
#define N_   1024
#define T_   16
#define E_   512
#define H_   8
#define DH_  64
#define KNN_ 16

typedef __attribute__((ext_vector_type(8))) _Float16 half8;
typedef __attribute__((ext_vector_type(4))) _Float16 half4;
typedef __attribute__((ext_vector_type(2))) _Float16 half2v;
typedef __attribute__((ext_vector_type(4))) float    f32x4;

// ---------------------------------------------------------------------------
// Kernel 1: KNN over positions + log_w. Unchanged (verified R3-R6).
// ---------------------------------------------------------------------------
__global__ __launch_bounds__(256) void knn_kernel(const float* __restrict__ pos,
                                                  const float* __restrict__ tau_p,
                                                  int* __restrict__ knn_idx,
                                                  float* __restrict__ logw) {
    __shared__ float dist[N_];
    __shared__ float rval[4];
    __shared__ int   ridx[4];
    __shared__ float sel_d[KNN_];
    __shared__ int   sel_i[KNN_];

    const int i = blockIdx.x;
    const int t = threadIdx.x;

    const float px = pos[2 * i], py = pos[2 * i + 1];
    const float xi2 = px * px + py * py;

    for (int j = t; j < N_; j += 256) {
        const float qx = pos[2 * j], qy = pos[2 * j + 1];
        const float xj2 = qx * qx + qy * qy;
        float d2 = xi2 + xj2 - 2.0f * (px * qx + py * qy);
        d2 = fmaxf(d2, 0.0f);
        const float d = sqrtf(d2 + 1e-9f);
        dist[j] = (j == i) ? __builtin_inff() : d;
    }
    __syncthreads();

    for (int k = 0; k < KNN_; ++k) {
        float best = __builtin_inff();
        int bi = 0x7fffffff;
        for (int j = t; j < N_; j += 256) {
            const float d = dist[j];
            if (d < best) { best = d; bi = j; }
        }
        for (int off = 32; off >= 1; off >>= 1) {
            const float ov = __shfl_down(best, off);
            const int   oi = __shfl_down(bi, off);
            if (ov < best || (ov == best && oi < bi)) { best = ov; bi = oi; }
        }
        const int wave = t >> 6;
        if ((t & 63) == 0) { rval[wave] = best; ridx[wave] = bi; }
        __syncthreads();
        if (t == 0) {
            for (int w = 1; w < 4; ++w) {
                if (rval[w] < best || (rval[w] == best && ridx[w] < bi)) { best = rval[w]; bi = ridx[w]; }
            }
            sel_d[k] = best;
            sel_i[k] = bi;
            dist[bi] = __builtin_inff();
        }
        __syncthreads();
    }

    if (t < KNN_) {
        float mean = 0.0f;
        for (int k = 0; k < KNN_; ++k) mean += sel_d[k];
        mean *= (1.0f / KNN_);
        const float scale = fmaxf(mean, 1.1920929e-7f);
        const float tau_safe = fmaxf(tau_p[0], 1e-4f);
        float lw = -(sel_d[t] / scale) / tau_safe;
        lw = fminf(fmaxf(lw, -10.0f), 0.0f);
        logw[i * KNN_ + t]    = lw;
        knn_idx[i * KNN_ + t] = sel_i[t];
    }
}

// ---------------------------------------------------------------------------
// Kernel 2: weight prep. Hi f16 for all four matrices; lo residual only for
// Wo (sole consumer of 2-pass precision). Layout in halves:
//   [0,WS) Wq_h  [WS,2WS) Wk_h  [2WS,3WS) Wv_h  [3WS,4WS) Wo_h  [4WS,5WS) Wo_l
// ---------------------------------------------------------------------------
__global__ __launch_bounds__(256) void wsplit_kernel(const float* __restrict__ Wq,
                                                     const float* __restrict__ Wk,
                                                     const float* __restrict__ Wv,
                                                     const float* __restrict__ Wo,
                                                     _Float16* __restrict__ dst) {
    const int id  = blockIdx.x * 256 + threadIdx.x;   // float4 units, 4*65536 total
    const int mat = id >> 16;
    const int i   = id & 65535;
    const float* src = (mat == 0) ? Wq : (mat == 1) ? Wk : (mat == 2) ? Wv : Wo;
    const float4 v = ((const float4*)src)[i];
    half4 hi, lo;
    const float* f = (const float*)&v;
#pragma unroll
    for (int j = 0; j < 4; ++j) {
        const _Float16 hh = (_Float16)f[j];
        hi[j] = hh;
        lo[j] = (_Float16)(f[j] - (float)hh);
    }
    *(half4*)(dst + (size_t)mat * 262144 + (size_t)i * 4) = hi;
    if (mat == 3)
        *(half4*)(dst + (size_t)4 * 262144 + (size_t)i * 4) = lo;
}

// ---------------------------------------------------------------------------
// Kernel 3: h_last/neigh_mean straight to f16. Unchanged (verified R6).
// ---------------------------------------------------------------------------
__global__ __launch_bounds__(256) void last_mean_kernel(const float* __restrict__ hidden,
                                                        _Float16* __restrict__ hlast_h,
                                                        _Float16* __restrict__ nmean_h) {
    const int idx = blockIdx.x * 256 + threadIdx.x;
    const int e4 = idx & (E_ / 4 - 1);
    const int bn = idx >> 7;
    const float4* h = (const float4*)hidden;
    const size_t base = (size_t)bn * (T_ * (E_ / 4)) + e4;
    const float4 a = h[base + 12 * (E_ / 4)];
    const float4 b = h[base + 13 * (E_ / 4)];
    const float4 c = h[base + 14 * (E_ / 4)];
    const float4 d = h[base + 15 * (E_ / 4)];
    half4 hl, nm;
    const float* df = (const float*)&d;
    const float* af = (const float*)&a;
    const float* bf = (const float*)&b;
    const float* cf = (const float*)&c;
#pragma unroll
    for (int j = 0; j < 4; ++j) {
        hl[j] = (_Float16)df[j];
        nm[j] = (_Float16)((af[j] + bf[j] + cf[j] + df[j]) * 0.25f);
    }
    *(half4*)(hlast_h + (size_t)idx * 4) = hl;
    *(half4*)(nmean_h + (size_t)idx * 4) = nm;
}

// ---------------------------------------------------------------------------
// f16 MFMA GEMM, m97 structure (verified R6): global_load_lds(16B), linear
// LDS both sides, 2-barrier K-loop, 128x128 tile, BK=64, 4 waves (2x2).
// PASSES=1: C = A*Wh          (Q/K/V; dropped A*Wl ~2.3e-4 ~= f16 out round)
// PASSES=2: C = A*Wh + A*Wl   (final out; dropped Al*W ~2.4e-4 << 0.0039)
// LDS: PASSES==1 -> 2 arrays x 16KB = 32KB; ==2 -> 48KB (R6-verified path).
// ---------------------------------------------------------------------------
__device__ __forceinline__ void gload16(const void* g, void* l) {
    __builtin_amdgcn_global_load_lds((const __attribute__((address_space(1))) void*)g,
                                     (__attribute__((address_space(3))) void*)l, 16, 0, 0);
}

template <int PASSES, typename OT>
__device__ __forceinline__ void gemm_f16(const _Float16* __restrict__ Ah,
                                         const _Float16* __restrict__ Wh,
                                         const _Float16* __restrict__ Wl,
                                         const float* __restrict__ bias,
                                         OT* __restrict__ C) {
    constexpr int NARR = PASSES + 1;                       // 2 or 3
    __shared__ unsigned short lds[NARR * 8192];            // NARR x 16KB

    const int t    = threadIdx.x;
    const int m0   = blockIdx.x * 128;
    const int j0   = blockIdx.y * 128;
    const int lane = t & 63;
    const int wv   = t >> 6;
    const int wm   = wv >> 1, wn = wv & 1;
    const int lr   = lane & 15, kg = lane >> 4;
    const int lsub = (lane >> 3) * 1024 + (lane & 7) * 16; // 8 rows x 128B per slab

    f32x4 acc[4][4];
    const f32x4 zero = {0.0f, 0.0f, 0.0f, 0.0f};
#pragma unroll
    for (int f = 0; f < 4; ++f)
#pragma unroll
        for (int g = 0; g < 4; ++g) acc[f][g] = zero;

    for (int it = 0; it < 8; ++it) {
        const size_t kb = (size_t)(it * 64) * 2;
        const char* gA  = (const char*)Ah + (size_t)m0 * 1024 + kb;
        const char* gWh = (const char*)Wh + (size_t)j0 * 1024 + kb;
        const char* gWl = (PASSES == 2) ? (const char*)Wl + (size_t)j0 * 1024 + kb : (const char*)0;
#pragma unroll
        for (int jj = 0; jj < NARR * 4; ++jj) {
            const int j = wv * (NARR * 4) + jj;
            const int arr = j >> 4, slab = j & 15;
            const char* gb = (arr == 0) ? gA : (arr == 1) ? gWh : gWl;
            gload16(gb + (size_t)slab * 8192 + lsub, (char*)lds + j * 1024);
        }
        __syncthreads();   // vmcnt(0) drained before barrier -> staged data ready

#pragma unroll
        for (int ks = 0; ks < 2; ++ks) {
            const int ko = ks * 64 + kg * 16;
            half8 ah[4], wh[4], wl[4];
#pragma unroll
            for (int f = 0; f < 4; ++f) {
                const int abyt = (wm * 64 + f * 16 + lr) * 128 + ko;
                ah[f] = *(const half8*)((const char*)lds + abyt);
            }
#pragma unroll
            for (int g = 0; g < 4; ++g) {
                const int wbyt = (wn * 64 + g * 16 + lr) * 128 + ko;
                wh[g] = *(const half8*)((const char*)lds + 16384 + wbyt);
                if (PASSES == 2) wl[g] = *(const half8*)((const char*)lds + 32768 + wbyt);
            }
#pragma unroll
            for (int f = 0; f < 4; ++f)
#pragma unroll
                for (int g = 0; g < 4; ++g)
                    acc[f][g] = __builtin_amdgcn_mfma_f32_16x16x32_f16(ah[f], wh[g], acc[f][g], 0, 0, 0);
            if (PASSES == 2) {
#pragma unroll
                for (int f = 0; f < 4; ++f)
#pragma unroll
                    for (int g = 0; g < 4; ++g)
                        acc[f][g] = __builtin_amdgcn_mfma_f32_16x16x32_f16(ah[f], wl[g], acc[f][g], 0, 0, 0);
            }
        }
        if (it < 7) __syncthreads();
    }

    // Epilogue (D layout col=lane&15, row=(lane>>4)*4+q — verified R4-R6)
#pragma unroll
    for (int g = 0; g < 4; ++g) {
        const int n = j0 + wn * 64 + g * 16 + lr;
        const float bn_ = bias[n];
#pragma unroll
        for (int f = 0; f < 4; ++f) {
            const int mrow = m0 + wm * 64 + f * 16 + kg * 4;
#pragma unroll
            for (int q = 0; q < 4; ++q)
                C[(size_t)(mrow + q) * 512 + n] = (OT)(acc[f][g][q] + bn_);
        }
    }
}

__global__ __launch_bounds__(256, 3) void qkv_gemm_kernel(const _Float16* __restrict__ hlast_h,
                                                          const _Float16* __restrict__ nmean_h,
                                                          const _Float16* __restrict__ Wsp,
                                                          const float* __restrict__ bq,
                                                          const float* __restrict__ bk,
                                                          const float* __restrict__ bv,
                                                          _Float16* __restrict__ Qh,
                                                          _Float16* __restrict__ Kh,
                                                          _Float16* __restrict__ Vh) {
    const int which = blockIdx.z;
    const size_t WS = 262144;
    const _Float16* A  = (which == 0) ? hlast_h : nmean_h;
    const _Float16* wh = Wsp + (size_t)which * WS;
    const float* bias  = (which == 0) ? bq : (which == 1) ? bk : bv;
    _Float16* Cc       = (which == 0) ? Qh : (which == 1) ? Kh : Vh;
    gemm_f16<1, _Float16>(A, wh, (const _Float16*)0, bias, Cc);
}

__global__ __launch_bounds__(256, 3) void out_gemm_kernel(const _Float16* __restrict__ ctx,
                                                          const _Float16* __restrict__ Wsp,
                                                          const float* __restrict__ bo,
                                                          float* __restrict__ out) {
    const size_t WS = 262144;
    gemm_f16<2, float>(ctx, Wsp + 3 * WS, Wsp + 4 * WS, bo, out);
}

// ---------------------------------------------------------------------------
// Kernel 5: attention. Single f16 ctx output (lo residual no longer needed).
// Otherwise unchanged (verified R6).
// ---------------------------------------------------------------------------
__global__ __launch_bounds__(256) void attn_kernel(const _Float16* __restrict__ Qh,
                                                   const _Float16* __restrict__ Kf,
                                                   const _Float16* __restrict__ Vf,
                                                   const int* __restrict__ knn_idx,
                                                   const float* __restrict__ logw,
                                                   _Float16* __restrict__ ctx) {
    const int bid = blockIdx.x;
    const int bn  = ((bid & 7) << 10) | (bid >> 3);
    const int n   = bn & (N_ - 1);
    const int b   = bn >> 10;
    const int t   = threadIdx.x;

    __shared__ int   idxs[KNN_];
    __shared__ float lws[KNN_];
    if (t < KNN_) {
        idxs[t] = knn_idx[n * KNN_ + t];
        lws[t]  = logw[n * KNN_ + t];
    }
    __syncthreads();

    const half2v q2 = ((const half2v*)Qh)[(size_t)bn * 256 + t];
    const float qx = (float)q2.x, qy = (float)q2.y;

    float logits[KNN_];
#pragma unroll
    for (int k = 0; k < KNN_; ++k) {
        const int j = idxs[k];
        const half2v kv = ((const half2v*)Kf)[((size_t)(b * N_ + j)) * 256 + t];
        float d = qx * (float)kv.x + qy * (float)kv.y;
        d += __shfl_xor(d, 1);
        d += __shfl_xor(d, 2);
        d += __shfl_xor(d, 4);
        d += __shfl_xor(d, 8);
        d += __shfl_xor(d, 16);
        logits[k] = d * 0.125f + lws[k];
    }

    float m = -__builtin_inff();
#pragma unroll
    for (int k = 0; k < KNN_; ++k) m = fmaxf(m, logits[k]);
    float p[KNN_];
    float s = 0.0f;
#pragma unroll
    for (int k = 0; k < KNN_; ++k) { p[k] = expf(logits[k] - m); s += p[k]; }
    const float inv = 1.0f / s;

    float2 acc = make_float2(0.0f, 0.0f);
#pragma unroll
    for (int k = 0; k < KNN_; ++k) {
        const int j = idxs[k];
        const half2v vv = ((const half2v*)Vf)[((size_t)(b * N_ + j)) * 256 + t];
        const float w = p[k] * inv;
        acc.x = fmaf(w, (float)vv.x, acc.x);
        acc.y = fmaf(w, (float)vv.y, acc.y);
    }
    half2v hx;
    hx.x = (_Float16)acc.x;
    hx.y = (_Float16)acc.y;
    ((half2v*)ctx)[(size_t)bn * 256 + t] = hx;
}

// ---------------------------------------------------------------------------
extern "C" void kernel_launch(void* const* d_in, const int* in_sizes, int n_in,
                              void* d_out, int out_size, void* d_ws, size_t ws_size,
                              hipStream_t stream) {
    const float* hidden = (const float*)d_in[0];
    const float* pos    = (const float*)d_in[1];
    const float* Wq     = (const float*)d_in[2];
    const float* bq     = (const float*)d_in[3];
    const float* Wk     = (const float*)d_in[4];
    const float* bk     = (const float*)d_in[5];
    const float* Wv     = (const float*)d_in[6];
    const float* bv     = (const float*)d_in[7];
    const float* Wo     = (const float*)d_in[8];
    const float* bo     = (const float*)d_in[9];
    const float* tau    = (const float*)d_in[10];

    _Float16* hp = (_Float16*)d_ws;
    const size_t SZH = (size_t)B_ * N_ * E_;   // 4,194,304 halves per array
    const size_t WS  = 262144;                 // 512*512 halves
    _Float16* hlast_h = hp;
    _Float16* nmean_h = hp + SZH;
    _Float16* Qh      = hp + 2 * SZH;
    _Float16* Kh      = hp + 3 * SZH;
    _Float16* Vh      = hp + 4 * SZH;
    _Float16* ctx     = hp + 5 * SZH;
    _Float16* Wsp     = hp + 6 * SZH;          // 5 * WS halves
    int*      knn_idx = (int*)(hp + 6 * SZH + 5 * WS);
    float*    logw    = (float*)(knn_idx + N_ * KNN_);
    float*    out     = (float*)d_out;

    knn_kernel<<<N_, 256, 0, stream>>>(pos, tau, knn_idx, logw);
    wsplit_kernel<<<1024, 256, 0, stream>>>(Wq, Wk, Wv, Wo, Wsp);
    last_mean_kernel<<<(B_ * N_ * E_ / 4) / 256, 256, 0, stream>>>(hidden, hlast_h, nmean_h);

    dim3 gqkv(B_ * N_ / 128, E_ / 128, 3);
    qkv_gemm_kernel<<<gqkv, 256, 0, stream>>>(hlast_h, nmean_h, Wsp, bq, bk, bv, Qh, Kh, Vh);

    attn_kernel<<<B_ * N_, 256, 0, stream>>>(Qh, Kh, Vh, knn_idx, logw, ctx);

    dim3 gout(B_ * N_ / 128, E_ / 128, 1);
    out_gemm_kernel<<<gout, 256, 0, stream>>>(ctx, Wsp, bo, out);
}